// Round 6
// baseline (131.931 us; speedup 1.0000x reference)
//
#include <hip/hip_runtime.h>
#include <hip/hip_bf16.h>
#include <stdint.h>

// Problem constants (B=1)
#define NN   256     // MSA depth (contraction K of GEMM1)
#define LL   192
#define MDIM 6144    // L*J
#define D2   1024    // J*J
#define FF   128     // n_feat_out

typedef __bf16 bf16x8 __attribute__((ext_vector_type(8)));
typedef float  f32x4  __attribute__((ext_vector_type(4)));

#define MFMA16(a, b, c) __builtin_amdgcn_mfma_f32_16x16x32_bf16(a, b, c, 0, 0, 0)

__device__ __forceinline__ void gload_lds16(const void* g, void* l) {
  __builtin_amdgcn_global_load_lds(
      (__attribute__((address_space(1))) void*)(g),
      (__attribute__((address_space(3))) void*)(l),
      16, 0, 0);
}

static __device__ __forceinline__ unsigned short bf16_bits(float v) {
  __bf16 h = (__bf16)v;
  return __builtin_bit_cast(unsigned short, h);
}

// ---------------------------------------------------------------------------
// prep_all v2 (unchanged): 64x64 tiles, ILP=4, padded [64][65] LDS.
//  blocks [0,384):   transpose x_down  [256][6144] f32 -> At [6144][256] bf16
//  blocks [384,768): transpose x_down_w            -> Bt
//  blocks [768,896): WB[fragment-linear] = bf16(a2*W), S = colsum, T = b2@W+b
// ---------------------------------------------------------------------------
__global__ __launch_bounds__(256)
void prep_all(const float* __restrict__ x1, const float* __restrict__ x2,
              const float* __restrict__ W, const float* __restrict__ a2,
              const float* __restrict__ b2, const float* __restrict__ bias,
              __bf16* __restrict__ At, __bf16* __restrict__ Bt,
              __bf16* __restrict__ WB, float* __restrict__ S,
              float* __restrict__ T) {
  __shared__ float tile[64][65];
  const int b = blockIdx.x;
  const int t = threadIdx.x;
  if (b < 768) {
    const float* src = (b < 384) ? x1 : x2;
    __bf16* dst = (b < 384) ? At : Bt;
    const int bb = (b < 384) ? b : b - 384;
    const int m0 = (bb % 96) * 64;
    const int k0 = (bb / 96) * 64;
    const int rr = t >> 4;
    const int cc = (t & 15) * 4;
#pragma unroll
    for (int it = 0; it < 4; ++it) {
      const int kr = rr + it * 16;
      const float4 v = *(const float4*)&src[(size_t)(k0 + kr) * MDIM + m0 + cc];
      tile[kr][cc + 0] = v.x;
      tile[kr][cc + 1] = v.y;
      tile[kr][cc + 2] = v.z;
      tile[kr][cc + 3] = v.w;
    }
    __syncthreads();
#pragma unroll
    for (int it = 0; it < 4; ++it) {
      const int mr = rr + it * 16;
      ushort4 u;
      u.x = bf16_bits(tile[cc + 0][mr]);
      u.y = bf16_bits(tile[cc + 1][mr]);
      u.z = bf16_bits(tile[cc + 2][mr]);
      u.w = bf16_bits(tile[cc + 3][mr]);
      *(ushort4*)&dst[(size_t)(m0 + mr) * NN + k0 + cc] = u;
    }
  } else {
    const int f = b - 768;
    float s = 0.f, tt = 0.f;
#pragma unroll
    for (int it = 0; it < 4; ++it) {
      const int k = t + it * 256;
      const float wv = W[(size_t)k * FF + f];
      const __bf16 wa = (__bf16)(a2[k] * wv);
      WB[(size_t)(k >> 5) * 4096 + f * 32 + ((k >> 3) & 3) * 8 + (k & 7)] = wa;
      s += (float)wa;
      tt += b2[k] * wv;
    }
#pragma unroll
    for (int off = 32; off; off >>= 1) {
      s += __shfl_xor(s, off);
      tt += __shfl_xor(tt, off);
    }
    const int wv_ = t >> 6, ln = t & 63;
    if (ln == 0) { tile[0][wv_] = s; tile[1][wv_] = tt; }
    __syncthreads();
    if (t == 0) {
      S[f] = tile[0][0] + tile[0][1] + tile[0][2] + tile[0][3];
      T[f] = tile[1][0] + tile[1][1] + tile[1][2] + tile[1][3] + bias[f];
    }
  }
}

// ---------------------------------------------------------------------------
// fused15 = fused10 with B de-staged (flatmm-style B-direct):
// Post-mortem chain: fused11 (geometry), 12/13 (dbuf pipelining), 14 (32x32
// MFMA) all regressed; fused10 (52.9us) is the structure. Its remaining
// serial cost: each K-chunk drains 48KB of DMA (A 16K + B 32K) at vmcnt(0)
// before compute. B-frags are wave-private under a 1m x 8n wave grid (each
// wave owns n-slice w*32..w*32+32), so B skips LDS entirely: per chunk each
// wave issues 4 x global 16B loads (direct to regs) between the barriers —
// latency hides under the A-drain window. Removes per block: 128KB LDS-write
// DMA, 256 B ds_reads, 2/3 of the drain bytes. L2 bytes UNCHANGED (B read
// once per block either way). Accumulation order per (kb,ks) identical to
// fused10 -> bitwise-same output.
//   - wave grid 1m x 8n: acc[8][2] f32x4 (64 regs, same); per ks: 8 A
//     ds_reads + 16 MFMA (same totals as fused10).
//   - LN mapping re-derived: r = (t8>>1)*8 + w; j = (t8&1)*16+q*4+reg;
//     mm = tj*16+c -> identical Xs content; GEMM2/epilogue byte-identical.
//   - A staging/swizzle unchanged (16KB, rows 0..127, each wave DMAs 16).
//   - Tripwires: WRITE_SIZE == 18432 KB exactly; conflicts DOWN vs 2.95M;
//     absmax 0.015625.
// out = rstd*(x@Wa - mean*S) + T
// ---------------------------------------------------------------------------
__global__ __launch_bounds__(512, 4)
void fused15(const __bf16* __restrict__ At, const __bf16* __restrict__ Bt,
             const __bf16* __restrict__ WB, const float* __restrict__ S,
             const float* __restrict__ T, float* __restrict__ out) {
  __shared__ uint8_t lds[65536];      // staging (A 16K @0) / Xs[32][2048]
  __shared__ float mean_s[32], rstd_s[32];

  const int tid = threadIdx.x;
  const int w = tid >> 6;            // wave 0..7
  const int lane = tid & 63;
  const int q = lane >> 4;           // quad
  const int c = lane & 15;

  // ---- XCD banding: b&7 = XCD (round-robin dispatch), 12x12 rectangle ----
  const int b = blockIdx.x;
  const int xcd = b & 7;
  const int s_ = b >> 3;             // 0..143
  const int bx = (xcd >> 1) * 12 + (s_ % 12);   // 0..47  (m, 128-wide)
  const int by = (xcd & 1) * 12 + (s_ / 12);    // 0..23  (n, 256-wide)
  const int m0 = bx * 128, n0 = by * 256;

  uint8_t* As = lds;                 // 128 rows x 128B

  // staging lane decomposition: 8 lanes per 128B row (BK=64 bf16)
  const int l8 = lane & 7;
  const int r8 = lane >> 3;
  const int gsw = l8 ^ r8;           // XOR-swizzled source 16B-group

  f32x4 acc[8][2];
#pragma unroll
  for (int i = 0; i < 8; ++i) {
    acc[i][0] = (f32x4){0.f, 0.f, 0.f, 0.f};
    acc[i][1] = (f32x4){0.f, 0.f, 0.f, 0.f};
  }

  // ---------------- GEMM1 K-loop: 4 chunks of BK=64 (rolled) ----------------
  {
    const __bf16* gA = At + (size_t)(m0 + w * 16 + r8) * NN + gsw * 8;
    // B direct-to-reg: wave w owns n-slice [n0+w*32, +32). Lane (q,c) reads
    // B[row = slice + tj*16 + c][k = kb*64 + ks*32 + q*8] (16B, aligned).
    const __bf16* gB0 = Bt + (size_t)(n0 + w * 32 + c) * NN + q * 8;
    const __bf16* gB1 = gB0 + (size_t)16 * NN;
#pragma unroll 1
    for (int kb = 0; kb < 4; ++kb) {
      __syncthreads();
      // A: 16 rows/wave (2 instr) into LDS
      gload_lds16(gA, As + (w * 16) * 128);
      gload_lds16(gA + (size_t)8 * NN, As + (w * 16 + 8) * 128);
      // B: 4 frags direct to regs; drained together with A by the barrier,
      // latency hidden under the (now 3x smaller) DMA drain window.
      const bf16x8 b00 = *(const bf16x8*)(gB0);        // tj=0, ks=0
      const bf16x8 b01 = *(const bf16x8*)(gB1);        // tj=1, ks=0
      const bf16x8 b10 = *(const bf16x8*)(gB0 + 32);   // tj=0, ks=1
      const bf16x8 b11 = *(const bf16x8*)(gB1 + 32);   // tj=1, ks=1
      __builtin_amdgcn_sched_barrier(0);   // pin the loads above the drain
      __syncthreads();
#pragma unroll
      for (int ks = 0; ks < 2; ++ks) {
        const bf16x8 bk0 = ks ? b10 : b00;
        const bf16x8 bk1 = ks ? b11 : b01;
        const int slot = ((ks * 4 + q) ^ l8) * 16;
#pragma unroll
        for (int t8 = 0; t8 < 8; ++t8) {
          const bf16x8 a = *(const bf16x8*)(As + (t8 * 16 + c) * 128 + slot);
          acc[t8][0] = MFMA16(a, bk0, acc[t8][0]);
          acc[t8][1] = MFMA16(a, bk1, acc[t8][1]);
        }
      }
      gA += 64;
      gB0 += 64;
      gB1 += 64;
    }
  }

  // ------------- GEMM2 depth-2 prefetch (held shallow while acc is live) -----
  const int fs = w * 16;             // this wave's 16-f slice
  const __bf16* wbp = WB + (fs + c) * 32 + q * 8;   // + kstep*4096 elements
  bf16x8 pb[8];
  pb[0] = *(const bf16x8*)(wbp);
  pb[1] = *(const bf16x8*)(wbp + 4096);

  __syncthreads();   // all staging ds_reads done; lds becomes Xs[32][2048]

  // ------------- LN stats (in-wave) + packed-b32 swizzled scatter -------------
  // Xs byte addr for element (row r, k): g=k>>3; G = g ^ (g>>4) ^ (r&7);
  // addr = r*2048 + G*16 + (k&7)*2   — identical map/content to fused10.
  // acc[t8][tj][reg] at lane (q,c) holds C[m][n]: m = t8*16 + q*4 + reg,
  // n = w*32 + tj*16 + c  ->  r = (t8>>1)*8 + w; j = (t8&1)*16 + q*4 + reg;
  // LN-k = j*32 + tj*16 + c.
#pragma unroll
  for (int rp4 = 0; rp4 < 4; ++rp4) {
    float s1 = 0.f, s2 = 0.f;
#pragma unroll
    for (int th = 0; th < 2; ++th)
#pragma unroll
      for (int tj = 0; tj < 2; ++tj)
#pragma unroll
        for (int reg = 0; reg < 4; ++reg) {
          const float v = acc[rp4 * 2 + th][tj][reg];
          s1 += v; s2 += v * v;
        }
#pragma unroll
    for (int off = 32; off; off >>= 1) {
      s1 += __shfl_xor(s1, off);
      s2 += __shfl_xor(s2, off);
    }
    const float mean = s1 * (1.0f / 1024.0f);
    const float var = s2 * (1.0f / 1024.0f) - mean * mean;
    const float rstd = rsqrtf(var + 1e-5f);
    const int r = rp4 * 8 + w;       // 0..31
    if (lane == 0) { mean_s[r] = mean; rstd_s[r] = rstd; }
    const int r7 = r & 7;
#pragma unroll
    for (int th = 0; th < 2; ++th)
#pragma unroll
      for (int tj = 0; tj < 2; ++tj)
#pragma unroll
        for (int rp = 0; rp < 4; rp += 2) {
          const float x = acc[rp4 * 2 + th][tj][rp];
          const float y = acc[rp4 * 2 + th][tj][rp + 1];
          const float send = (c & 1) ? x : y;
          const float recv = __shfl_xor(send, 1);
          const float vlo = (c & 1) ? recv : x;
          const float vhi = (c & 1) ? y : recv;
          const int reg_w = (c & 1) ? rp + 1 : rp;
          const int j = th * 16 + q * 4 + reg_w;
          const int mm0 = tj * 16 + (c & ~1);
          const int k = j * 32 + mm0;
          const int g = k >> 3;
          const int G = g ^ (g >> 4) ^ r7;
          const uint32_t dw =
              ((uint32_t)bf16_bits(vhi) << 16) | (uint32_t)bf16_bits(vlo);
          *(uint32_t*)(lds + r * 2048 + G * 16 + (mm0 & 7) * 2) = dw;
        }
  }

  __syncthreads();   // Xs + stats visible; acc DEAD below
  __builtin_amdgcn_sched_barrier(0);   // pin the deepening loads BELOW here

  // ------------- deepen WB pipeline to 8 (acc registers freed) -------------
#pragma unroll
  for (int p = 2; p < 8; ++p)
    pb[p] = *(const bf16x8*)(wbp + p * 4096);

  // ------------- GEMM2: Xs(32x1024) @ Wa^T -> 32x16 (per wave), depth-8 ------
  f32x4 acc2[2];
  acc2[0] = (f32x4){0.f, 0.f, 0.f, 0.f};
  acc2[1] = (f32x4){0.f, 0.f, 0.f, 0.f};
  const int c7 = c & 7;
#pragma unroll
  for (int kstep = 0; kstep < 32; ++kstep) {
    const int g = kstep * 4 + q;
    const int G = g ^ (g >> 4) ^ c7;
    const bf16x8 a0 = *(const bf16x8*)(lds + c * 2048 + G * 16);
    const bf16x8 a1 = *(const bf16x8*)(lds + (16 + c) * 2048 + G * 16);
    acc2[0] = MFMA16(a0, pb[kstep & 7], acc2[0]);
    acc2[1] = MFMA16(a1, pb[kstep & 7], acc2[1]);
    if (kstep < 24)
      pb[kstep & 7] = *(const bf16x8*)(wbp + (kstep + 8) * 4096);
  }

  // ------------- epilogue: affine + store (S/T loaded only now) -------------
  const float S0 = S[fs + c], T0 = T[fs + c];
#pragma unroll
  for (int reg = 0; reg < 4; ++reg) {
    const int r0 = q * 4 + reg;            // LN rows 0..15 (acc2[0])
    const int r1 = 16 + r0;                // LN rows 16..31 (acc2[1])
    {
      const float mean = mean_s[r0], rstd = rstd_s[r0];
      const int i = bx * 4 + (r0 >> 3);
      const int l = by * 8 + (r0 & 7);
      out[((size_t)i * LL + l) * FF + fs + c] =
          rstd * (acc2[0][reg] - mean * S0) + T0;
    }
    {
      const float mean = mean_s[r1], rstd = rstd_s[r1];
      const int i = bx * 4 + (r1 >> 3);
      const int l = by * 8 + (r1 & 7);
      out[((size_t)i * LL + l) * FF + fs + c] =
          rstd * (acc2[1][reg] - mean * S0) + T0;
    }
  }
}

// ---------------------------------------------------------------------------
extern "C" void kernel_launch(void* const* d_in, const int* in_sizes, int n_in,
                              void* d_out, int out_size, void* d_ws, size_t ws_size,
                              hipStream_t stream) {
  const float* x_down   = (const float*)d_in[0];
  const float* x_down_w = (const float*)d_in[1];
  const float* a2       = (const float*)d_in[2];
  const float* b2       = (const float*)d_in[3];
  const float* W        = (const float*)d_in[4];
  const float* bias     = (const float*)d_in[5];
  float* out = (float*)d_out;

  uint8_t* ws = (uint8_t*)d_ws;
  __bf16* At  = (__bf16*)(ws);                 // 6144*256*2 = 3145728 B
  __bf16* Bt  = (__bf16*)(ws + 3145728);       // 3145728 B
  __bf16* WB  = (__bf16*)(ws + 6291456);       // 128*1024*2 = 262144 B
  float*  S   = (float*)(ws + 6553600);        // 512 B
  float*  T   = (float*)(ws + 6554112);        // 512 B

  prep_all<<<dim3(896), dim3(256), 0, stream>>>(x_down, x_down_w, W, a2, b2,
                                                bias, At, Bt, WB, S, T);
  fused15<<<dim3(1152), dim3(512), 0, stream>>>(At, Bt, WB, S, T, out);
}

// Round 7
// 123.642 us; speedup vs baseline: 1.0670x; 1.0670x over previous
//
#include <hip/hip_runtime.h>
#include <hip/hip_bf16.h>
#include <stdint.h>

// Problem constants (B=1)
#define NN   256     // MSA depth (contraction K of GEMM1)
#define LL   192
#define MDIM 6144    // L*J
#define D2   1024    // J*J
#define FF   128     // n_feat_out

typedef __bf16 bf16x8 __attribute__((ext_vector_type(8)));
typedef float  f32x4  __attribute__((ext_vector_type(4)));

#define MFMA16(a, b, c) __builtin_amdgcn_mfma_f32_16x16x32_bf16(a, b, c, 0, 0, 0)

__device__ __forceinline__ void gload_lds16(const void* g, void* l) {
  __builtin_amdgcn_global_load_lds(
      (__attribute__((address_space(1))) void*)(g),
      (__attribute__((address_space(3))) void*)(l),
      16, 0, 0);
}

static __device__ __forceinline__ unsigned short bf16_bits(float v) {
  __bf16 h = (__bf16)v;
  return __builtin_bit_cast(unsigned short, h);
}

// ---------------------------------------------------------------------------
// prep_all v2 (unchanged): 64x64 tiles, ILP=4, padded [64][65] LDS.
//  blocks [0,384):   transpose x_down  [256][6144] f32 -> At [6144][256] bf16
//  blocks [384,768): transpose x_down_w            -> Bt
//  blocks [768,896): WB[fragment-linear] = bf16(a2*W), S = colsum, T = b2@W+b
// ---------------------------------------------------------------------------
__global__ __launch_bounds__(256)
void prep_all(const float* __restrict__ x1, const float* __restrict__ x2,
              const float* __restrict__ W, const float* __restrict__ a2,
              const float* __restrict__ b2, const float* __restrict__ bias,
              __bf16* __restrict__ At, __bf16* __restrict__ Bt,
              __bf16* __restrict__ WB, float* __restrict__ S,
              float* __restrict__ T) {
  __shared__ float tile[64][65];
  const int b = blockIdx.x;
  const int t = threadIdx.x;
  if (b < 768) {
    const float* src = (b < 384) ? x1 : x2;
    __bf16* dst = (b < 384) ? At : Bt;
    const int bb = (b < 384) ? b : b - 384;
    const int m0 = (bb % 96) * 64;
    const int k0 = (bb / 96) * 64;
    const int rr = t >> 4;
    const int cc = (t & 15) * 4;
#pragma unroll
    for (int it = 0; it < 4; ++it) {
      const int kr = rr + it * 16;
      const float4 v = *(const float4*)&src[(size_t)(k0 + kr) * MDIM + m0 + cc];
      tile[kr][cc + 0] = v.x;
      tile[kr][cc + 1] = v.y;
      tile[kr][cc + 2] = v.z;
      tile[kr][cc + 3] = v.w;
    }
    __syncthreads();
#pragma unroll
    for (int it = 0; it < 4; ++it) {
      const int mr = rr + it * 16;
      ushort4 u;
      u.x = bf16_bits(tile[cc + 0][mr]);
      u.y = bf16_bits(tile[cc + 1][mr]);
      u.z = bf16_bits(tile[cc + 2][mr]);
      u.w = bf16_bits(tile[cc + 3][mr]);
      *(ushort4*)&dst[(size_t)(m0 + mr) * NN + k0 + cc] = u;
    }
  } else {
    const int f = b - 768;
    float s = 0.f, tt = 0.f;
#pragma unroll
    for (int it = 0; it < 4; ++it) {
      const int k = t + it * 256;
      const float wv = W[(size_t)k * FF + f];
      const __bf16 wa = (__bf16)(a2[k] * wv);
      WB[(size_t)(k >> 5) * 4096 + f * 32 + ((k >> 3) & 3) * 8 + (k & 7)] = wa;
      s += (float)wa;
      tt += b2[k] * wv;
    }
#pragma unroll
    for (int off = 32; off; off >>= 1) {
      s += __shfl_xor(s, off);
      tt += __shfl_xor(tt, off);
    }
    const int wv_ = t >> 6, ln = t & 63;
    if (ln == 0) { tile[0][wv_] = s; tile[1][wv_] = tt; }
    __syncthreads();
    if (t == 0) {
      S[f] = tile[0][0] + tile[0][1] + tile[0][2] + tile[0][3];
      T[f] = tile[1][0] + tile[1][1] + tile[1][2] + tile[1][3] + bias[f];
    }
  }
}

// ---------------------------------------------------------------------------
// fused16 = EXACT fused10 (proven best: 52.8us fused / 124.56us total) with
// ONE zero-risk change: non-temporal epilogue stores. Rationale: the 18.9MB
// out stream is never re-read; plain stores allocate it in L2 where it
// competes with the At/Bt/WB read streams. nt (write-around) preserves panel
// residency. Everything else byte-identical to the verified kernel.
// Post-mortem ledger (all within-session, all counters clean):
//   fused11 geometry 256^2/1-blk-CU: +5.0us (occupancy loss)
//   fused12 dbuf BK=32 unrolled:     +4.8us (spill, WRITE 29.8MB)
//   fused13 dbuf BK=32 rolled:       +6.3us (no spill; structural conflicts
//                                    5.3M + 2x barrier count)
//   fused14 32x32x16 MFMA:           +6.1us (frag-read aliasing 4.7M + dep chains)
//   fused15 B-direct flatmm:         +7.5us (64B-segment B loads; conflicts
//                                    2949120 == fused10 exactly -> B was
//                                    never the conflict source)
// Tripwires: WRITE_SIZE == 18432 KB exactly; VGPR 60; conflicts 2949120.
// out = rstd*(x@Wa - mean*S) + T
// ---------------------------------------------------------------------------
__global__ __launch_bounds__(512, 4)
void fused16(const __bf16* __restrict__ At, const __bf16* __restrict__ Bt,
             const __bf16* __restrict__ WB, const float* __restrict__ S,
             const float* __restrict__ T, float* __restrict__ out) {
  __shared__ uint8_t lds[65536];      // staging (A 16K @0, B 32K @16K) / Xs[32][2048]
  __shared__ float mean_s[32], rstd_s[32];

  const int tid = threadIdx.x;
  const int w = tid >> 6;            // wave 0..7
  const int lane = tid & 63;
  const int q = lane >> 4;           // quad
  const int c = lane & 15;

  // ---- XCD banding: b&7 = XCD (round-robin dispatch), 12x12 rectangle ----
  const int b = blockIdx.x;
  const int xcd = b & 7;
  const int s_ = b >> 3;             // 0..143
  const int bx = (xcd >> 1) * 12 + (s_ % 12);   // 0..47  (m, 128-wide)
  const int by = (xcd & 1) * 12 + (s_ / 12);    // 0..23  (n, 256-wide)
  const int m0 = bx * 128, n0 = by * 256;

  uint8_t* As = lds;                 // 128 rows x 128B
  uint8_t* Bs = lds + 16384;         // 256 rows x 128B

  // staging lane decomposition: 8 lanes per 128B row (BK=64 bf16)
  const int l8 = lane & 7;
  const int r8 = lane >> 3;
  const int gsw = l8 ^ r8;           // XOR-swizzled source 16B-group

  f32x4 acc[4][4];
#pragma unroll
  for (int i = 0; i < 4; ++i)
#pragma unroll
    for (int j = 0; j < 4; ++j)
      acc[i][j] = (f32x4){0.f, 0.f, 0.f, 0.f};

  const int mbase = (w & 1) * 64;    // wave grid 2(m) x 4(n)
  const int nbase = (w >> 1) * 64;

  // ---------------- GEMM1 K-loop: 4 chunks of BK=64 (rolled) ----------------
  {
    const __bf16* gA = At + (size_t)(m0 + w * 16 + r8) * NN + gsw * 8;
    const __bf16* gB = Bt + (size_t)(n0 + w * 32 + r8) * NN + gsw * 8;
#pragma unroll 1
    for (int kb = 0; kb < 4; ++kb) {
      __syncthreads();
      // A: 16 rows/wave (2 instr), B: 32 rows/wave (4 instr)
#pragma unroll
      for (int j = 0; j < 2; ++j)
        gload_lds16(gA + (size_t)j * 8 * NN, As + (w * 16 + j * 8) * 128);
#pragma unroll
      for (int j = 0; j < 4; ++j)
        gload_lds16(gB + (size_t)j * 8 * NN, Bs + (w * 32 + j * 8) * 128);
      __syncthreads();
#pragma unroll
      for (int ks = 0; ks < 2; ++ks) {
        const int slot = ((ks * 4 + q) ^ (lane & 7)) * 16;
        bf16x8 a[4];
#pragma unroll
        for (int t4 = 0; t4 < 4; ++t4)
          a[t4] = *(const bf16x8*)(As + (mbase + t4 * 16 + c) * 128 + slot);
#pragma unroll
        for (int tj = 0; tj < 4; ++tj) {
          const bf16x8 bfr =
              *(const bf16x8*)(Bs + (nbase + tj * 16 + c) * 128 + slot);
#pragma unroll
          for (int ti = 0; ti < 4; ++ti)
            acc[ti][tj] = MFMA16(a[ti], bfr, acc[ti][tj]);
        }
      }
      gA += 64;
      gB += 64;
    }
  }

  // ------------- GEMM2 depth-2 prefetch (held shallow while acc is live) -----
  const int fs = w * 16;             // this wave's 16-f slice
  const __bf16* wbp = WB + (fs + c) * 32 + q * 8;   // + kstep*4096 elements
  bf16x8 pb[8];
  pb[0] = *(const bf16x8*)(wbp);
  pb[1] = *(const bf16x8*)(wbp + 4096);

  __syncthreads();   // all staging ds_reads done; lds becomes Xs[32][2048]

  // ------------- LN stats (in-wave) + packed-b32 swizzled scatter -------------
  // Xs byte addr for element (row r, k): g=k>>3; G = g ^ (g>>4) ^ (r&7);
  // addr = r*2048 + G*16 + (k&7)*2
  const int i_hi = w & 1, l_hi = w >> 1;   // i_local = i_hi*2+ab, l_local = l_hi*2+cb
#pragma unroll
  for (int ab = 0; ab < 2; ++ab) {
#pragma unroll
    for (int cb = 0; cb < 2; ++cb) {
      float s1 = 0.f, s2 = 0.f;
#pragma unroll
      for (int dti = 0; dti < 2; ++dti)
#pragma unroll
        for (int dtj = 0; dtj < 2; ++dtj)
#pragma unroll
          for (int reg = 0; reg < 4; ++reg) {
            const float v = acc[ab * 2 + dti][cb * 2 + dtj][reg];
            s1 += v; s2 += v * v;
          }
#pragma unroll
      for (int off = 32; off; off >>= 1) {
        s1 += __shfl_xor(s1, off);
        s2 += __shfl_xor(s2, off);
      }
      const float mean = s1 * (1.0f / 1024.0f);
      const float var = s2 * (1.0f / 1024.0f) - mean * mean;
      const float rstd = rsqrtf(var + 1e-5f);
      const int r = (i_hi * 2 + ab) * 8 + l_hi * 2 + cb;   // 0..31
      if (lane == 0) { mean_s[r] = mean; rstd_s[r] = rstd; }
      const int r7 = r & 7;
#pragma unroll
      for (int dti = 0; dti < 2; ++dti)
#pragma unroll
        for (int dtj = 0; dtj < 2; ++dtj)
#pragma unroll
          for (int rp = 0; rp < 4; rp += 2) {
            const float x = acc[ab * 2 + dti][cb * 2 + dtj][rp];
            const float y = acc[ab * 2 + dti][cb * 2 + dtj][rp + 1];
            const float send = (c & 1) ? x : y;
            const float recv = __shfl_xor(send, 1);
            const float vlo = (c & 1) ? recv : x;
            const float vhi = (c & 1) ? y : recv;
            const int reg_w = (c & 1) ? rp + 1 : rp;
            const int j = dti * 16 + q * 4 + reg_w;
            const int mm0 = dtj * 16 + (c & ~1);
            const int k = j * 32 + mm0;
            const int g = k >> 3;
            const int G = g ^ (g >> 4) ^ r7;
            const uint32_t dw =
                ((uint32_t)bf16_bits(vhi) << 16) | (uint32_t)bf16_bits(vlo);
            *(uint32_t*)(lds + r * 2048 + G * 16 + (mm0 & 7) * 2) = dw;
          }
    }
  }

  __syncthreads();   // Xs + stats visible; acc DEAD below
  __builtin_amdgcn_sched_barrier(0);   // pin the deepening loads BELOW here

  // ------------- deepen WB pipeline to 8 (acc registers freed) -------------
#pragma unroll
  for (int p = 2; p < 8; ++p)
    pb[p] = *(const bf16x8*)(wbp + p * 4096);

  // ------------- GEMM2: Xs(32x1024) @ Wa^T -> 32x16 (per wave), depth-8 ------
  f32x4 acc2[2];
  acc2[0] = (f32x4){0.f, 0.f, 0.f, 0.f};
  acc2[1] = (f32x4){0.f, 0.f, 0.f, 0.f};
  const int c7 = c & 7;
#pragma unroll
  for (int kstep = 0; kstep < 32; ++kstep) {
    const int g = kstep * 4 + q;
    const int G = g ^ (g >> 4) ^ c7;
    const bf16x8 a0 = *(const bf16x8*)(lds + c * 2048 + G * 16);
    const bf16x8 a1 = *(const bf16x8*)(lds + (16 + c) * 2048 + G * 16);
    acc2[0] = MFMA16(a0, pb[kstep & 7], acc2[0]);
    acc2[1] = MFMA16(a1, pb[kstep & 7], acc2[1]);
    if (kstep < 24)
      pb[kstep & 7] = *(const bf16x8*)(wbp + (kstep + 8) * 4096);
  }

  // ------------- epilogue: affine + nt store (out never re-read; keep L2
  // residency for At/Bt/WB streams) -------------
  const float S0 = S[fs + c], T0 = T[fs + c];
#pragma unroll
  for (int reg = 0; reg < 4; ++reg) {
    const int r0 = q * 4 + reg;            // LN rows 0..15 (acc2[0])
    const int r1 = 16 + r0;                // LN rows 16..31 (acc2[1])
    {
      const float mean = mean_s[r0], rstd = rstd_s[r0];
      const int i = bx * 4 + (r0 >> 3);
      const int l = by * 8 + (r0 & 7);
      __builtin_nontemporal_store(rstd * (acc2[0][reg] - mean * S0) + T0,
                                  &out[((size_t)i * LL + l) * FF + fs + c]);
    }
    {
      const float mean = mean_s[r1], rstd = rstd_s[r1];
      const int i = bx * 4 + (r1 >> 3);
      const int l = by * 8 + (r1 & 7);
      __builtin_nontemporal_store(rstd * (acc2[1][reg] - mean * S0) + T0,
                                  &out[((size_t)i * LL + l) * FF + fs + c]);
    }
  }
}

// ---------------------------------------------------------------------------
extern "C" void kernel_launch(void* const* d_in, const int* in_sizes, int n_in,
                              void* d_out, int out_size, void* d_ws, size_t ws_size,
                              hipStream_t stream) {
  const float* x_down   = (const float*)d_in[0];
  const float* x_down_w = (const float*)d_in[1];
  const float* a2       = (const float*)d_in[2];
  const float* b2       = (const float*)d_in[3];
  const float* W        = (const float*)d_in[4];
  const float* bias     = (const float*)d_in[5];
  float* out = (float*)d_out;

  uint8_t* ws = (uint8_t*)d_ws;
  __bf16* At  = (__bf16*)(ws);                 // 6144*256*2 = 3145728 B
  __bf16* Bt  = (__bf16*)(ws + 3145728);       // 3145728 B
  __bf16* WB  = (__bf16*)(ws + 6291456);       // 128*1024*2 = 262144 B
  float*  S   = (float*)(ws + 6553600);        // 512 B
  float*  T   = (float*)(ws + 6554112);        // 512 B

  prep_all<<<dim3(896), dim3(256), 0, stream>>>(x_down, x_down_w, W, a2, b2,
                                                bias, At, Bt, WB, S, T);
  fused16<<<dim3(1152), dim3(512), 0, stream>>>(At, Bt, WB, S, T, out);
}

// Round 8
// 122.649 us; speedup vs baseline: 1.0757x; 1.0081x over previous
//
#include <hip/hip_runtime.h>
#include <hip/hip_bf16.h>
#include <stdint.h>

// Problem constants (B=1)
#define NN   256     // MSA depth (contraction K of GEMM1)
#define LL   192
#define MDIM 6144    // L*J
#define D2   1024    // J*J
#define FF   128     // n_feat_out

typedef __bf16 bf16x8 __attribute__((ext_vector_type(8)));
typedef float  f32x4  __attribute__((ext_vector_type(4)));

#define MFMA16(a, b, c) __builtin_amdgcn_mfma_f32_16x16x32_bf16(a, b, c, 0, 0, 0)

__device__ __forceinline__ void gload_lds16(const void* g, void* l) {
  __builtin_amdgcn_global_load_lds(
      (__attribute__((address_space(1))) void*)(g),
      (__attribute__((address_space(3))) void*)(l),
      16, 0, 0);
}

static __device__ __forceinline__ unsigned short bf16_bits(float v) {
  __bf16 h = (__bf16)v;
  return __builtin_bit_cast(unsigned short, h);
}

// ---------------------------------------------------------------------------
// prep_all v2: 64x64 tiles, ILP=4, padded [64][65] LDS.
//  blocks [0,384):   transpose x_down  [256][6144] f32 -> At [6144][256] bf16
//  blocks [384,768): transpose x_down_w            -> Bt
//  blocks [768,896): WB[fragment-linear] = bf16(a2*W), S = colsum, T = b2@W+b
// ---------------------------------------------------------------------------
__global__ __launch_bounds__(256)
void prep_all(const float* __restrict__ x1, const float* __restrict__ x2,
              const float* __restrict__ W, const float* __restrict__ a2,
              const float* __restrict__ b2, const float* __restrict__ bias,
              __bf16* __restrict__ At, __bf16* __restrict__ Bt,
              __bf16* __restrict__ WB, float* __restrict__ S,
              float* __restrict__ T) {
  __shared__ float tile[64][65];
  const int b = blockIdx.x;
  const int t = threadIdx.x;
  if (b < 768) {
    const float* src = (b < 384) ? x1 : x2;
    __bf16* dst = (b < 384) ? At : Bt;
    const int bb = (b < 384) ? b : b - 384;
    const int m0 = (bb % 96) * 64;
    const int k0 = (bb / 96) * 64;
    const int rr = t >> 4;
    const int cc = (t & 15) * 4;
#pragma unroll
    for (int it = 0; it < 4; ++it) {
      const int kr = rr + it * 16;
      const float4 v = *(const float4*)&src[(size_t)(k0 + kr) * MDIM + m0 + cc];
      tile[kr][cc + 0] = v.x;
      tile[kr][cc + 1] = v.y;
      tile[kr][cc + 2] = v.z;
      tile[kr][cc + 3] = v.w;
    }
    __syncthreads();
#pragma unroll
    for (int it = 0; it < 4; ++it) {
      const int mr = rr + it * 16;
      ushort4 u;
      u.x = bf16_bits(tile[cc + 0][mr]);
      u.y = bf16_bits(tile[cc + 1][mr]);
      u.z = bf16_bits(tile[cc + 2][mr]);
      u.w = bf16_bits(tile[cc + 3][mr]);
      *(ushort4*)&dst[(size_t)(m0 + mr) * NN + k0 + cc] = u;
    }
  } else {
    const int f = b - 768;
    float s = 0.f, tt = 0.f;
#pragma unroll
    for (int it = 0; it < 4; ++it) {
      const int k = t + it * 256;
      const float wv = W[(size_t)k * FF + f];
      const __bf16 wa = (__bf16)(a2[k] * wv);
      WB[(size_t)(k >> 5) * 4096 + f * 32 + ((k >> 3) & 3) * 8 + (k & 7)] = wa;
      s += (float)wa;
      tt += b2[k] * wv;
    }
#pragma unroll
    for (int off = 32; off; off >>= 1) {
      s += __shfl_xor(s, off);
      tt += __shfl_xor(tt, off);
    }
    const int wv_ = t >> 6, ln = t & 63;
    if (ln == 0) { tile[0][wv_] = s; tile[1][wv_] = tt; }
    __syncthreads();
    if (t == 0) {
      S[f] = tile[0][0] + tile[0][1] + tile[0][2] + tile[0][3];
      T[f] = tile[1][0] + tile[1][1] + tile[1][2] + tile[1][3] + bias[f];
    }
  }
}

// ---------------------------------------------------------------------------
// fused10 — the verified local optimum (52.8us fused dispatch, best of 7
// structural variants). Session falsification ledger (dispatch-time deltas,
// each counter-diagnosed):
//   fused11 256^2/1-blk-CU geometry:  +5.0us (Occupancy 25.8%, lost overlap)
//   fused12 dbuf BK=32 unrolled:      +4.8us (spill, WRITE 29.8MB)
//   fused13 dbuf BK=32 rolled:        +6.3us (structural conflicts 5.3M, 2x barriers)
//   fused14 32x32x16 MFMA:            +6.1us (frag aliasing 4.7M + dep chains)
//   fused15 B-direct flatmm:          +7.5us (64B-segment loads; conflicts
//                                     unchanged 2949120 -> B exonerated)
//   fused16 nt epilogue stores:       +1.8us (partial-line HBM writes,
//                                     WRITE 18432->23200KB)
// The co-resident block (2/CU) provides the staging-drain overlap that
// explicit pipelining failed to beat. All pipes <32% busy: latency-structured
// local optimum, not a counter roofline.
// Tripwires: WRITE_SIZE == 18432 KB exactly; conflicts 2949120; VGPR 60.
// out = rstd*(x@Wa - mean*S) + T
// ---------------------------------------------------------------------------
__global__ __launch_bounds__(512, 4)
void fused10(const __bf16* __restrict__ At, const __bf16* __restrict__ Bt,
             const __bf16* __restrict__ WB, const float* __restrict__ S,
             const float* __restrict__ T, float* __restrict__ out) {
  __shared__ uint8_t lds[65536];      // staging (A 16K @0, B 32K @16K) / Xs[32][2048]
  __shared__ float mean_s[32], rstd_s[32];

  const int tid = threadIdx.x;
  const int w = tid >> 6;            // wave 0..7
  const int lane = tid & 63;
  const int q = lane >> 4;           // quad
  const int c = lane & 15;

  // ---- XCD banding: b&7 = XCD (round-robin dispatch), 12x12 rectangle ----
  const int b = blockIdx.x;
  const int xcd = b & 7;
  const int s_ = b >> 3;             // 0..143
  const int bx = (xcd >> 1) * 12 + (s_ % 12);   // 0..47  (m, 128-wide)
  const int by = (xcd & 1) * 12 + (s_ / 12);    // 0..23  (n, 256-wide)
  const int m0 = bx * 128, n0 = by * 256;

  uint8_t* As = lds;                 // 128 rows x 128B
  uint8_t* Bs = lds + 16384;         // 256 rows x 128B

  // staging lane decomposition: 8 lanes per 128B row (BK=64 bf16)
  const int l8 = lane & 7;
  const int r8 = lane >> 3;
  const int gsw = l8 ^ r8;           // XOR-swizzled source 16B-group

  f32x4 acc[4][4];
#pragma unroll
  for (int i = 0; i < 4; ++i)
#pragma unroll
    for (int j = 0; j < 4; ++j)
      acc[i][j] = (f32x4){0.f, 0.f, 0.f, 0.f};

  const int mbase = (w & 1) * 64;    // wave grid 2(m) x 4(n)
  const int nbase = (w >> 1) * 64;

  // ---------------- GEMM1 K-loop: 4 chunks of BK=64 (rolled) ----------------
  {
    const __bf16* gA = At + (size_t)(m0 + w * 16 + r8) * NN + gsw * 8;
    const __bf16* gB = Bt + (size_t)(n0 + w * 32 + r8) * NN + gsw * 8;
#pragma unroll 1
    for (int kb = 0; kb < 4; ++kb) {
      __syncthreads();
      // A: 16 rows/wave (2 instr), B: 32 rows/wave (4 instr)
#pragma unroll
      for (int j = 0; j < 2; ++j)
        gload_lds16(gA + (size_t)j * 8 * NN, As + (w * 16 + j * 8) * 128);
#pragma unroll
      for (int j = 0; j < 4; ++j)
        gload_lds16(gB + (size_t)j * 8 * NN, Bs + (w * 32 + j * 8) * 128);
      __syncthreads();
#pragma unroll
      for (int ks = 0; ks < 2; ++ks) {
        const int slot = ((ks * 4 + q) ^ (lane & 7)) * 16;
        bf16x8 a[4];
#pragma unroll
        for (int t4 = 0; t4 < 4; ++t4)
          a[t4] = *(const bf16x8*)(As + (mbase + t4 * 16 + c) * 128 + slot);
#pragma unroll
        for (int tj = 0; tj < 4; ++tj) {
          const bf16x8 bfr =
              *(const bf16x8*)(Bs + (nbase + tj * 16 + c) * 128 + slot);
#pragma unroll
          for (int ti = 0; ti < 4; ++ti)
            acc[ti][tj] = MFMA16(a[ti], bfr, acc[ti][tj]);
        }
      }
      gA += 64;
      gB += 64;
    }
  }

  // ------------- GEMM2 depth-2 prefetch (held shallow while acc is live) -----
  const int fs = w * 16;             // this wave's 16-f slice
  const __bf16* wbp = WB + (fs + c) * 32 + q * 8;   // + kstep*4096 elements
  bf16x8 pb[8];
  pb[0] = *(const bf16x8*)(wbp);
  pb[1] = *(const bf16x8*)(wbp + 4096);

  __syncthreads();   // all staging ds_reads done; lds becomes Xs[32][2048]

  // ------------- LN stats (in-wave) + packed-b32 swizzled scatter -------------
  // Xs byte addr for element (row r, k): g=k>>3; G = g ^ (g>>4) ^ (r&7);
  // addr = r*2048 + G*16 + (k&7)*2
  const int i_hi = w & 1, l_hi = w >> 1;   // i_local = i_hi*2+ab, l_local = l_hi*2+cb
#pragma unroll
  for (int ab = 0; ab < 2; ++ab) {
#pragma unroll
    for (int cb = 0; cb < 2; ++cb) {
      float s1 = 0.f, s2 = 0.f;
#pragma unroll
      for (int dti = 0; dti < 2; ++dti)
#pragma unroll
        for (int dtj = 0; dtj < 2; ++dtj)
#pragma unroll
          for (int reg = 0; reg < 4; ++reg) {
            const float v = acc[ab * 2 + dti][cb * 2 + dtj][reg];
            s1 += v; s2 += v * v;
          }
#pragma unroll
      for (int off = 32; off; off >>= 1) {
        s1 += __shfl_xor(s1, off);
        s2 += __shfl_xor(s2, off);
      }
      const float mean = s1 * (1.0f / 1024.0f);
      const float var = s2 * (1.0f / 1024.0f) - mean * mean;
      const float rstd = rsqrtf(var + 1e-5f);
      const int r = (i_hi * 2 + ab) * 8 + l_hi * 2 + cb;   // 0..31
      if (lane == 0) { mean_s[r] = mean; rstd_s[r] = rstd; }
      const int r7 = r & 7;
#pragma unroll
      for (int dti = 0; dti < 2; ++dti)
#pragma unroll
        for (int dtj = 0; dtj < 2; ++dtj)
#pragma unroll
          for (int rp = 0; rp < 4; rp += 2) {
            const float x = acc[ab * 2 + dti][cb * 2 + dtj][rp];
            const float y = acc[ab * 2 + dti][cb * 2 + dtj][rp + 1];
            const float send = (c & 1) ? x : y;
            const float recv = __shfl_xor(send, 1);
            const float vlo = (c & 1) ? recv : x;
            const float vhi = (c & 1) ? y : recv;
            const int reg_w = (c & 1) ? rp + 1 : rp;
            const int j = dti * 16 + q * 4 + reg_w;
            const int mm0 = dtj * 16 + (c & ~1);
            const int k = j * 32 + mm0;
            const int g = k >> 3;
            const int G = g ^ (g >> 4) ^ r7;
            const uint32_t dw =
                ((uint32_t)bf16_bits(vhi) << 16) | (uint32_t)bf16_bits(vlo);
            *(uint32_t*)(lds + r * 2048 + G * 16 + (mm0 & 7) * 2) = dw;
          }
    }
  }

  __syncthreads();   // Xs + stats visible; acc DEAD below
  __builtin_amdgcn_sched_barrier(0);   // pin the deepening loads BELOW here

  // ------------- deepen WB pipeline to 8 (acc registers freed) -------------
#pragma unroll
  for (int p = 2; p < 8; ++p)
    pb[p] = *(const bf16x8*)(wbp + p * 4096);

  // ------------- GEMM2: Xs(32x1024) @ Wa^T -> 32x16 (per wave), depth-8 ------
  f32x4 acc2[2];
  acc2[0] = (f32x4){0.f, 0.f, 0.f, 0.f};
  acc2[1] = (f32x4){0.f, 0.f, 0.f, 0.f};
  const int c7 = c & 7;
#pragma unroll
  for (int kstep = 0; kstep < 32; ++kstep) {
    const int g = kstep * 4 + q;
    const int G = g ^ (g >> 4) ^ c7;
    const bf16x8 a0 = *(const bf16x8*)(lds + c * 2048 + G * 16);
    const bf16x8 a1 = *(const bf16x8*)(lds + (16 + c) * 2048 + G * 16);
    acc2[0] = MFMA16(a0, pb[kstep & 7], acc2[0]);
    acc2[1] = MFMA16(a1, pb[kstep & 7], acc2[1]);
    if (kstep < 24)
      pb[kstep & 7] = *(const bf16x8*)(wbp + (kstep + 8) * 4096);
  }

  // ------------- epilogue: affine + store (S/T loaded only now) -------------
  const float S0 = S[fs + c], T0 = T[fs + c];
#pragma unroll
  for (int reg = 0; reg < 4; ++reg) {
    const int r0 = q * 4 + reg;            // LN rows 0..15 (acc2[0])
    const int r1 = 16 + r0;                // LN rows 16..31 (acc2[1])
    {
      const float mean = mean_s[r0], rstd = rstd_s[r0];
      const int i = bx * 4 + (r0 >> 3);
      const int l = by * 8 + (r0 & 7);
      out[((size_t)i * LL + l) * FF + fs + c] =
          rstd * (acc2[0][reg] - mean * S0) + T0;
    }
    {
      const float mean = mean_s[r1], rstd = rstd_s[r1];
      const int i = bx * 4 + (r1 >> 3);
      const int l = by * 8 + (r1 & 7);
      out[((size_t)i * LL + l) * FF + fs + c] =
          rstd * (acc2[1][reg] - mean * S0) + T0;
    }
  }
}

// ---------------------------------------------------------------------------
extern "C" void kernel_launch(void* const* d_in, const int* in_sizes, int n_in,
                              void* d_out, int out_size, void* d_ws, size_t ws_size,
                              hipStream_t stream) {
  const float* x_down   = (const float*)d_in[0];
  const float* x_down_w = (const float*)d_in[1];
  const float* a2       = (const float*)d_in[2];
  const float* b2       = (const float*)d_in[3];
  const float* W        = (const float*)d_in[4];
  const float* bias     = (const float*)d_in[5];
  float* out = (float*)d_out;

  uint8_t* ws = (uint8_t*)d_ws;
  __bf16* At  = (__bf16*)(ws);                 // 6144*256*2 = 3145728 B
  __bf16* Bt  = (__bf16*)(ws + 3145728);       // 3145728 B
  __bf16* WB  = (__bf16*)(ws + 6291456);       // 128*1024*2 = 262144 B
  float*  S   = (float*)(ws + 6553600);        // 512 B
  float*  T   = (float*)(ws + 6554112);        // 512 B

  prep_all<<<dim3(896), dim3(256), 0, stream>>>(x_down, x_down_w, W, a2, b2,
                                                bias, At, Bt, WB, S, T);
  fused10<<<dim3(1152), dim3(512), 0, stream>>>(At, Bt, WB, S, T, out);
}